// Round 6
// baseline (5901.763 us; speedup 1.0000x reference)
//
#include <hip/hip_runtime.h>
#include <stdint.h>

// ---------------- static problem config ----------------
#define S_TOT 21504
#define M_TOK 86016
// levels: (32,32) start 0, (64,64) start 1024, (128,128) start 5120

typedef __attribute__((ext_vector_type(8))) short bf16x8;
typedef __attribute__((ext_vector_type(4))) float f32x4;
typedef __attribute__((ext_vector_type(2))) float f32x2;

__device__ __forceinline__ unsigned short f2b(float f) {
  union { float f; unsigned u; } v; v.f = f;
  unsigned r = v.u + 0x7FFFu + ((v.u >> 16) & 1u);
  return (unsigned short)(r >> 16);
}
__device__ __forceinline__ float b2f(unsigned short h) {
  union { unsigned u; float f; } v; v.u = ((unsigned)h) << 16;
  return v.f;
}
__device__ __forceinline__ float blo(unsigned u) {
  union { unsigned u; float f; } v; v.u = u << 16; return v.f;
}
__device__ __forceinline__ float bhi(unsigned u) {
  union { unsigned u; float f; } v; v.u = u & 0xffff0000u; return v.f;
}
__device__ __forceinline__ f32x2 unpk(unsigned u) {
  union { unsigned u; float f; } lo, hi;
  lo.u = u << 16; hi.u = u & 0xffff0000u;
  return (f32x2){lo.f, hi.f};
}

// ---------------- bf16 MFMA GEMM: C[M,N] = A[M,K] * Bt[N,K]^T + bias ----------------
// BM=BN=128, BK=64, 256 threads (4 waves, 64x64 quadrant each).
// Round-3 reg-staged structure (known good); BK=64 halves barriers; LDS row
// stride 72 elems (144 B, 16B-aligned) makes ds_write/read_b128 bank-uniform.
#define LSTR 72
template <int RELU>
__global__ __launch_bounds__(256) void gemm_kernel(
    const unsigned short* __restrict__ A, const unsigned short* __restrict__ Bt,
    const float* __restrict__ bias, const float* __restrict__ bias2, int nsplit,
    unsigned short* __restrict__ C, int N, int K) {
  __shared__ unsigned short Alds[128 * LSTR];
  __shared__ unsigned short Blds[128 * LSTR];
  const int tid = threadIdx.x;
  const int wave = tid >> 6, lane = tid & 63;
  const long m0 = (long)blockIdx.x * 128;
  const int n0 = blockIdx.y * 128;
  const int wm = (wave >> 1) * 64, wn = (wave & 1) * 64;
  const int l15 = lane & 15, lhi = lane >> 4;

  f32x4 acc[4][4];
#pragma unroll
  for (int i = 0; i < 4; i++)
#pragma unroll
    for (int j = 0; j < 4; j++) acc[i][j] = (f32x4){0.f, 0.f, 0.f, 0.f};

  // staging: 2 threads per row; thread covers 4 consecutive 16B chunks.
  // row = tid>>1, k-base = (tid&1)*32, chunk c at +c*8 elems.
  const int srow = tid >> 1, skb = (tid & 1) * 32;
  int brow = n0 + srow; if (brow >= N) brow = N - 1;  // clamp OOB weight rows
  const unsigned short* ap = A + (m0 + srow) * (long)K + skb;
  const unsigned short* bp = Bt + (long)brow * K + skb;
  unsigned short* asl = Alds + srow * LSTR + skb;
  unsigned short* bsl = Blds + srow * LSTR + skb;

  uint4 pa[4], pb[4];
#pragma unroll
  for (int c = 0; c < 4; c++) {
    pa[c] = *(const uint4*)(ap + c * 8);
    pb[c] = *(const uint4*)(bp + c * 8);
  }

  for (int k0 = 0; k0 < K; k0 += 64) {
    if (k0) __syncthreads();  // prior iteration's frag reads complete
#pragma unroll
    for (int c = 0; c < 4; c++) {
      *(uint4*)(asl + c * 8) = pa[c];
      *(uint4*)(bsl + c * 8) = pb[c];
    }
    if (k0 + 64 < K) {  // prefetch next K-tile; latency hides under MFMA
#pragma unroll
      for (int c = 0; c < 4; c++) {
        pa[c] = *(const uint4*)(ap + k0 + 64 + c * 8);
        pb[c] = *(const uint4*)(bp + k0 + 64 + c * 8);
      }
    }
    __syncthreads();

#pragma unroll
    for (int half = 0; half < 2; half++) {
      const int kk = half * 32 + lhi * 8;
      bf16x8 af[4], bq[4];
#pragma unroll
      for (int i = 0; i < 4; i++)
        af[i] = *(const bf16x8*)&Alds[(wm + i * 16 + l15) * LSTR + kk];
#pragma unroll
      for (int j = 0; j < 4; j++)
        bq[j] = *(const bf16x8*)&Blds[(wn + j * 16 + l15) * LSTR + kk];
#pragma unroll
      for (int i = 0; i < 4; i++)
#pragma unroll
        for (int j = 0; j < 4; j++)
          acc[i][j] = __builtin_amdgcn_mfma_f32_16x16x32_bf16(af[i], bq[j], acc[i][j], 0, 0, 0);
    }
  }

  const int rowb = lhi * 4;
#pragma unroll
  for (int j = 0; j < 4; j++) {
    const int n = n0 + wn + j * 16 + l15;
    if (n < N) {
      const float bn = (n < nsplit) ? bias[n] : bias2[n - nsplit];
#pragma unroll
      for (int i = 0; i < 4; i++) {
#pragma unroll
        for (int r = 0; r < 4; r++) {
          const long m = m0 + wm + i * 16 + rowb + r;
          float v = acc[i][j][r] + bn;
          if (RELU) v = fmaxf(v, 0.f);
          C[m * N + n] = f2b(v);
        }
      }
    }
  }
}

// ---------------- weight transpose + bf16 convert: [L][K][N] -> [L][N][K] ----------------
__global__ void wtrans_kernel(const float* __restrict__ src, unsigned short* __restrict__ dst,
                              int K, int N, size_t src_lstride, size_t dst_lstride) {
  __shared__ float t[32][33];
  const int tx = threadIdx.x, ty = threadIdx.y;
  const int n0 = blockIdx.x * 32, k0 = blockIdx.y * 32, l = blockIdx.z;
  src += (size_t)l * src_lstride;
  dst += (size_t)l * dst_lstride;
#pragma unroll
  for (int i = 0; i < 4; i++) t[ty * 4 + i][tx] = src[(size_t)(k0 + ty * 4 + i) * N + n0 + tx];
  __syncthreads();
#pragma unroll
  for (int i = 0; i < 4; i++)
    dst[(size_t)(n0 + ty * 4 + i) * K + k0 + tx] = f2b(t[tx][ty * 4 + i]);
}

// ---------------- flatten [B,C,H,W] -> [B,HW,C]; writes out f32/b16, pos b16, q b16 ----
__global__ void flatten_kernel(const float* __restrict__ src, const float* __restrict__ pos,
                               const float* __restrict__ lemb, float* __restrict__ outf,
                               unsigned short* __restrict__ outb, unsigned short* __restrict__ posb,
                               unsigned short* __restrict__ qb, int HW, int s0) {
  __shared__ float ts[32][33];
  __shared__ float tp[32][33];
  const int tx = threadIdx.x, ty = threadIdx.y;
  const int hw0 = blockIdx.x * 32, c0 = blockIdx.y * 32, b = blockIdx.z;
  const size_t ibase = ((size_t)b * 256 + c0) * HW + hw0;
#pragma unroll
  for (int i = 0; i < 4; i++) {
    ts[ty * 4 + i][tx] = src[ibase + (size_t)(ty * 4 + i) * HW + tx];
    tp[ty * 4 + i][tx] = pos[ibase + (size_t)(ty * 4 + i) * HW + tx];
  }
  __syncthreads();
#pragma unroll
  for (int i = 0; i < 4; i++) {
    const int sI = s0 + hw0 + ty * 4 + i, c = c0 + tx;
    const size_t o = ((size_t)b * S_TOT + sI) * 256 + c;
    const float sv = ts[tx][ty * 4 + i];
    const unsigned short pb = f2b(tp[tx][ty * 4 + i] + lemb[c]);
    outf[o] = sv;
    outb[o] = f2b(sv);
    posb[o] = pb;
    qb[o] = f2b(sv + b2f(pb));
  }
}

// ---------------- deformable attention sampling (oa = fused [offs(192) | aw(96)]) ----------
__global__ __launch_bounds__(256) void deform_kernel(const unsigned short* __restrict__ value,
                                                     const unsigned short* __restrict__ oa,
                                                     unsigned short* __restrict__ attn) {
  __shared__ float law[4][96];
  __shared__ uint4 didx[4][96];
  __shared__ float4 dwt[4][96];
  const int tid = threadIdx.x;
  const int wv = tid >> 6, lane = tid & 63;
  const int bs = blockIdx.x * 4 + wv;
  const int b = bs / S_TOT, s = bs - b * S_TOT;

  if (lane < 8) {  // per-head softmax over NL*NP=12
    const unsigned short* ap = oa + (size_t)bs * 288 + 192 + lane * 12;
    const uint2 p0 = *(const uint2*)ap;
    const uint2 p1 = *(const uint2*)(ap + 4);
    const uint2 p2 = *(const uint2*)(ap + 8);
    float a[12] = {blo(p0.x), bhi(p0.x), blo(p0.y), bhi(p0.y),
                   blo(p1.x), bhi(p1.x), blo(p1.y), bhi(p1.y),
                   blo(p2.x), bhi(p2.x), blo(p2.y), bhi(p2.y)};
    float mx = a[0];
#pragma unroll
    for (int i = 1; i < 12; i++) mx = fmaxf(mx, a[i]);
    float e[12], sm = 0.f;
#pragma unroll
    for (int i = 0; i < 12; i++) { e[i] = __expf(a[i] - mx); sm += e[i]; }
    const float r = 1.f / sm;
#pragma unroll
    for (int i = 0; i < 12; i++) law[wv][lane * 12 + i] = e[i] * r;
  }
  __syncthreads();

  float rx, ry;
  {
    if (s < 1024) { const int li = s; rx = ((li & 31) + 0.5f) * (1.f / 32); ry = ((li >> 5) + 0.5f) * (1.f / 32); }
    else if (s < 5120) { const int li = s - 1024; rx = ((li & 63) + 0.5f) * (1.f / 64); ry = ((li >> 6) + 0.5f) * (1.f / 64); }
    else { const int li = s - 5120; rx = ((li & 127) + 0.5f) * (1.f / 128); ry = ((li >> 7) + 0.5f) * (1.f / 128); }
  }

  for (int ti = lane; ti < 96; ti += 64) {
    const int h = ti / 12;
    const int rem = ti - h * 12;
    const int lvl = rem >> 2;
    const int wl = 32 << lvl;
    const float fwl = (float)wl;
    const int start = (lvl == 0) ? 0 : ((lvl == 1) ? 1024 : 5120);
    const unsigned op = *(const unsigned*)(oa + (size_t)bs * 288 + 2 * ti);
    const float ox = blo(op), oy = bhi(op);
    const float x = (rx + ox / fwl) * fwl - 0.5f;   // matches ref FP order
    const float y = (ry + oy / fwl) * fwl - 0.5f;
    const float xf = floorf(x), yf = floorf(y);
    const int x0 = (int)xf, y0 = (int)yf;
    const float fx = x - xf, fy = y - yf;
    const bool xv0 = (x0 >= 0) & (x0 < wl), xv1 = (x0 + 1 >= 0) & (x0 + 1 < wl);
    const bool yv0 = (y0 >= 0) & (y0 < wl), yv1 = (y0 + 1 >= 0) & (y0 + 1 < wl);
    const int x0c = min(max(x0, 0), wl - 1), x1c = min(max(x0 + 1, 0), wl - 1);
    const int y0c = min(max(y0, 0), wl - 1), y1c = min(max(y0 + 1, 0), wl - 1);
    const float w = law[wv][ti];
    float4 w4;
    w4.x = (xv0 & yv0) ? w * (1.f - fx) * (1.f - fy) : 0.f;
    w4.y = (xv1 & yv0) ? w * fx * (1.f - fy) : 0.f;
    w4.z = (xv0 & yv1) ? w * (1.f - fx) * fy : 0.f;
    w4.w = (xv1 & yv1) ? w * fx * fy : 0.f;
    const int base = ((b * S_TOT + start) << 8) + h * 32;
    uint4 iv;
    iv.x = base + (unsigned)(y0c * wl + x0c) * 256u;
    iv.y = base + (unsigned)(y0c * wl + x1c) * 256u;
    iv.z = base + (unsigned)(y1c * wl + x0c) * 256u;
    iv.w = base + (unsigned)(y1c * wl + x1c) * 256u;
    didx[wv][ti] = iv;
    dwt[wv][ti] = w4;
  }
  __syncthreads();

  const int h = lane >> 3, c = (lane & 7) * 4;
  const uint4* ip = &didx[wv][h * 12];
  const float4* wp = &dwt[wv][h * 12];
  f32x2 acc0 = (f32x2){0.f, 0.f}, acc1 = (f32x2){0.f, 0.f};
#pragma unroll 4
  for (int t = 0; t < 12; t++) {
    const uint4 iv = ip[t];
    const float4 w4 = wp[t];
    const uint2 q00 = *(const uint2*)(value + iv.x + c);
    const uint2 q01 = *(const uint2*)(value + iv.y + c);
    const uint2 q10 = *(const uint2*)(value + iv.z + c);
    const uint2 q11 = *(const uint2*)(value + iv.w + c);
    const f32x2 w0 = (f32x2){w4.x, w4.x}, w1 = (f32x2){w4.y, w4.y};
    const f32x2 w2 = (f32x2){w4.z, w4.z}, w3 = (f32x2){w4.w, w4.w};
    acc0 += w0 * unpk(q00.x) + w1 * unpk(q01.x) + w2 * unpk(q10.x) + w3 * unpk(q11.x);
    acc1 += w0 * unpk(q00.y) + w1 * unpk(q01.y) + w2 * unpk(q10.y) + w3 * unpk(q11.y);
  }
  uint2 o;
  o.x = (unsigned)f2b(acc0.x) | ((unsigned)f2b(acc0.y) << 16);
  o.y = (unsigned)f2b(acc1.x) | ((unsigned)f2b(acc1.y) << 16);
  *(uint2*)(attn + (size_t)bs * 256 + h * 32 + c) = o;
}

// ---------------- residual + layernorm (one wave per token); r is bf16 ----------------
__global__ __launch_bounds__(256) void resln_kernel(const float* __restrict__ x,
                                                    const unsigned short* __restrict__ r,
                                                    const float* __restrict__ g,
                                                    const float* __restrict__ bta,
                                                    float* __restrict__ of,
                                                    unsigned short* __restrict__ ob,
                                                    const unsigned short* __restrict__ pos,
                                                    unsigned short* __restrict__ qb) {
  const int t = blockIdx.x * 4 + (threadIdx.x >> 6);
  const int lane = threadIdx.x & 63;
  const size_t base = (size_t)t * 256;
  const float4 xv = ((const float4*)(x + base))[lane];
  const ushort4 rv = ((const ushort4*)(r + base))[lane];
  const float v0 = xv.x + b2f(rv.x), v1 = xv.y + b2f(rv.y);
  const float v2 = xv.z + b2f(rv.z), v3 = xv.w + b2f(rv.w);
  float sm = v0 + v1 + v2 + v3;
#pragma unroll
  for (int o = 32; o > 0; o >>= 1) sm += __shfl_xor(sm, o);
  const float mean = sm * (1.f / 256.f);
  const float d0 = v0 - mean, d1 = v1 - mean, d2 = v2 - mean, d3 = v3 - mean;
  float vs = d0 * d0 + d1 * d1 + d2 * d2 + d3 * d3;
#pragma unroll
  for (int o = 32; o > 0; o >>= 1) vs += __shfl_xor(vs, o);
  const float inv = rsqrtf(vs * (1.f / 256.f) + 1e-5f);
  const int c = lane * 4;
  const float o0 = d0 * inv * g[c] + bta[c];
  const float o1 = d1 * inv * g[c + 1] + bta[c + 1];
  const float o2 = d2 * inv * g[c + 2] + bta[c + 2];
  const float o3 = d3 * inv * g[c + 3] + bta[c + 3];
  ((float4*)(of + base))[lane] = make_float4(o0, o1, o2, o3);
  if (ob) {
    ushort4 u;
    u.x = f2b(o0); u.y = f2b(o1); u.z = f2b(o2); u.w = f2b(o3);
    ((ushort4*)(ob + base))[lane] = u;
  }
  if (qb) {
    const ushort4 pv = ((const ushort4*)(pos + base))[lane];
    ushort4 u;
    u.x = f2b(o0 + b2f(pv.x)); u.y = f2b(o1 + b2f(pv.y));
    u.z = f2b(o2 + b2f(pv.z)); u.w = f2b(o3 + b2f(pv.w));
    ((ushort4*)(qb + base))[lane] = u;
  }
}

// ---------------- host ----------------
extern "C" void kernel_launch(void* const* d_in, const int* in_sizes, int n_in,
                              void* d_out, int out_size, void* d_ws, size_t ws_size,
                              hipStream_t stream) {
  (void)in_sizes; (void)n_in; (void)out_size;
  const float* src0 = (const float*)d_in[0];
  const float* pos0 = (const float*)d_in[1];
  const float* src1 = (const float*)d_in[2];
  const float* pos1 = (const float*)d_in[3];
  const float* src2 = (const float*)d_in[4];
  const float* pos2 = (const float*)d_in[5];
  const float* lemb = (const float*)d_in[6];
  const float* Wv = (const float*)d_in[7];   const float* bv = (const float*)d_in[8];
  const float* Wo = (const float*)d_in[9];   const float* bo = (const float*)d_in[10];
  const float* Wa = (const float*)d_in[11];  const float* ba = (const float*)d_in[12];
  const float* Wout = (const float*)d_in[13]; const float* bout = (const float*)d_in[14];
  const float* ln1g = (const float*)d_in[15]; const float* ln1b = (const float*)d_in[16];
  const float* W1 = (const float*)d_in[17];  const float* b1 = (const float*)d_in[18];
  const float* W2 = (const float*)d_in[19];  const float* b2 = (const float*)d_in[20];
  const float* ln2g = (const float*)d_in[21]; const float* ln2b = (const float*)d_in[22];

  const size_t M = M_TOK;
  const size_t NEED = 44040192ull + 176160768ull + 44040192ull + 44040192ull + 8749056ull;
  if (ws_size < NEED) return;

  char* ws = (char*)d_ws;
  unsigned short* buf16 = (unsigned short*)ws;      ws += 44040192ull;
  char* ov = ws;                                    ws += 176160768ull;
  unsigned short* q_b16 = (unsigned short*)ov;
  unsigned short* oa_b16 = (unsigned short*)ov + M * 256;   // [M,288]: offs(192)|aw(96)
  unsigned short* attn_b16 = (unsigned short*)ov + M * 544;
  unsigned short* h_b16 = (unsigned short*)ov;  // clobbers q/oa/attn (dead by then)
  unsigned short* out_b16 = (unsigned short*)ws;    ws += 44040192ull;
  unsigned short* pos_b16 = (unsigned short*)ws;    ws += 44040192ull;
  unsigned short* wt = (unsigned short*)ws;

  unsigned short* wtv = wt;                 // [6][256][256]
  unsigned short* wtoa = wt + 393216;       // [6][288][256] (Wo rows 0..191, Wa rows 192..287)
  unsigned short* wtw = wt + 835584;        // [6][256][256]
  unsigned short* wt1 = wt + 1228800;       // [6][1024][256]
  unsigned short* wt2 = wt + 2801664;       // [6][256][1024]

  float* out_f32 = (float*)d_out;  // residual stream lives in d_out

  const dim3 b32(32, 8);
  wtrans_kernel<<<dim3(8, 8, 6), b32, 0, stream>>>(Wv, wtv, 256, 256, 65536, 65536);
  wtrans_kernel<<<dim3(6, 8, 6), b32, 0, stream>>>(Wo, wtoa, 256, 192, 49152, 73728);
  wtrans_kernel<<<dim3(3, 8, 6), b32, 0, stream>>>(Wa, wtoa + 192 * 256, 256, 96, 24576, 73728);
  wtrans_kernel<<<dim3(8, 8, 6), b32, 0, stream>>>(Wout, wtw, 256, 256, 65536, 65536);
  wtrans_kernel<<<dim3(32, 8, 6), b32, 0, stream>>>(W1, wt1, 256, 1024, 262144, 262144);
  wtrans_kernel<<<dim3(8, 32, 6), b32, 0, stream>>>(W2, wt2, 1024, 256, 262144, 262144);

  flatten_kernel<<<dim3(32, 8, 4), b32, 0, stream>>>(src0, pos0, lemb, out_f32, out_b16, pos_b16, q_b16, 1024, 0);
  flatten_kernel<<<dim3(128, 8, 4), b32, 0, stream>>>(src1, pos1, lemb + 256, out_f32, out_b16, pos_b16, q_b16, 4096, 1024);
  flatten_kernel<<<dim3(512, 8, 4), b32, 0, stream>>>(src2, pos2, lemb + 512, out_f32, out_b16, pos_b16, q_b16, 16384, 5120);

  for (int l = 0; l < 6; l++) {
    gemm_kernel<0><<<dim3(672, 2), 256, 0, stream>>>(out_b16, wtv + l * 65536, bv + l * 256, bv + l * 256, 256, buf16, 256, 256);
    gemm_kernel<0><<<dim3(672, 3), 256, 0, stream>>>(q_b16, wtoa + l * 73728, bo + l * 192, ba + l * 96, 192, oa_b16, 288, 256);
    deform_kernel<<<21504, 256, 0, stream>>>(buf16, oa_b16, attn_b16);
    gemm_kernel<0><<<dim3(672, 2), 256, 0, stream>>>(attn_b16, wtw + l * 65536, bout + l * 256, bout + l * 256, 256, buf16, 256, 256);
    resln_kernel<<<21504, 256, 0, stream>>>(out_f32, buf16, ln1g + l * 256, ln1b + l * 256, out_f32, out_b16, nullptr, nullptr);
    gemm_kernel<1><<<dim3(672, 8), 256, 0, stream>>>(out_b16, wt1 + l * 262144, b1 + l * 1024, b1 + l * 1024, 1024, h_b16, 1024, 256);
    gemm_kernel<0><<<dim3(672, 2), 256, 0, stream>>>(h_b16, wt2 + l * 262144, b2 + l * 256, b2 + l * 256, 256, buf16, 256, 1024);
    resln_kernel<<<21504, 256, 0, stream>>>(out_f32, buf16, ln2g + l * 256, ln2b + l * 256, out_f32,
                                            (l == 5) ? nullptr : out_b16,
                                            (l == 5) ? nullptr : pos_b16,
                                            (l == 5) ? nullptr : q_b16);
  }
}

// Round 7
// 4720.405 us; speedup vs baseline: 1.2503x; 1.2503x over previous
//
#include <hip/hip_runtime.h>
#include <stdint.h>

// ---------------- static problem config ----------------
#define S_TOT 21504
#define M_TOK 86016
// levels: (32,32) start 0, (64,64) start 1024, (128,128) start 5120

typedef __attribute__((ext_vector_type(8))) short bf16x8;
typedef __attribute__((ext_vector_type(4))) float f32x4;
typedef __attribute__((ext_vector_type(2))) float f32x2;

__device__ __forceinline__ unsigned short f2b(float f) {
  union { float f; unsigned u; } v; v.f = f;
  unsigned r = v.u + 0x7FFFu + ((v.u >> 16) & 1u);
  return (unsigned short)(r >> 16);
}
__device__ __forceinline__ float b2f(unsigned short h) {
  union { unsigned u; float f; } v; v.u = ((unsigned)h) << 16;
  return v.f;
}
__device__ __forceinline__ float blo(unsigned u) {
  union { unsigned u; float f; } v; v.u = u << 16; return v.f;
}
__device__ __forceinline__ float bhi(unsigned u) {
  union { unsigned u; float f; } v; v.u = u & 0xffff0000u; return v.f;
}
__device__ __forceinline__ f32x2 unpk(unsigned u) {
  union { unsigned u; float f; } lo, hi;
  lo.u = u << 16; hi.u = u & 0xffff0000u;
  return (f32x2){lo.f, hi.f};
}

// ---------------- direct-fragment bf16 MFMA GEMM (no LDS, no barriers) ----------------
// C[M,N] = A[M,K] * Bt[N,K]^T + bias.  BM=BN=128, 4 waves, 64x64 quadrant each.
// Key fact: the 16x16x32 A/B fragment (lane l15,lhi -> row l15, k lhi*8..+7) is a
// 16B-aligned contiguous dwordx4 in row-major [.][K] storage -> load fragments
// straight from global (L1/L2-hot), skipping LDS entirely. Depth-1 SW pipeline
// with two named register sets (X/Y) so all indexing is compile-time static.
template <int RELU, int KSTEPS>
__global__ __launch_bounds__(256) void gemm_direct(
    const unsigned short* __restrict__ A, const unsigned short* __restrict__ Bt,
    const float* __restrict__ bias, const float* __restrict__ bias2, int nsplit,
    unsigned short* __restrict__ C, int N) {
  constexpr int K = KSTEPS * 32;
  const int tid = threadIdx.x;
  const int wave = tid >> 6, lane = tid & 63;
  const long m0 = (long)blockIdx.x * 128;
  const int n0 = blockIdx.y * 128;
  const int wm = (wave >> 1) * 64, wn = (wave & 1) * 64;
  const int l15 = lane & 15, lhi = lane >> 4;

  const unsigned short* ap[4];
  const unsigned short* bp[4];
#pragma unroll
  for (int i = 0; i < 4; i++)
    ap[i] = A + (m0 + wm + i * 16 + l15) * (long)K + lhi * 8;
#pragma unroll
  for (int j = 0; j < 4; j++) {
    int rn = n0 + wn + j * 16 + l15;
    if (rn >= N) rn = N - 1;  // clamp OOB weight rows (results masked at store)
    bp[j] = Bt + (size_t)rn * K + lhi * 8;
  }

  f32x4 acc[4][4];
#pragma unroll
  for (int i = 0; i < 4; i++)
#pragma unroll
    for (int j = 0; j < 4; j++) acc[i][j] = (f32x4){0.f, 0.f, 0.f, 0.f};

  bf16x8 aX[4], bX[4], aY[4], bY[4];
#pragma unroll
  for (int i = 0; i < 4; i++) aX[i] = *(const bf16x8*)(ap[i]);
#pragma unroll
  for (int j = 0; j < 4; j++) bX[j] = *(const bf16x8*)(bp[j]);

#pragma unroll
  for (int s = 0; s < KSTEPS; s += 2) {
    if (s + 1 < KSTEPS) {  // prefetch step s+1 into Y while X computes
#pragma unroll
      for (int i = 0; i < 4; i++) aY[i] = *(const bf16x8*)(ap[i] + (s + 1) * 32);
#pragma unroll
      for (int j = 0; j < 4; j++) bY[j] = *(const bf16x8*)(bp[j] + (s + 1) * 32);
    }
#pragma unroll
    for (int i = 0; i < 4; i++)
#pragma unroll
      for (int j = 0; j < 4; j++)
        acc[i][j] = __builtin_amdgcn_mfma_f32_16x16x32_bf16(aX[i], bX[j], acc[i][j], 0, 0, 0);
    if (s + 2 < KSTEPS) {  // prefetch step s+2 into X while Y computes
#pragma unroll
      for (int i = 0; i < 4; i++) aX[i] = *(const bf16x8*)(ap[i] + (s + 2) * 32);
#pragma unroll
      for (int j = 0; j < 4; j++) bX[j] = *(const bf16x8*)(bp[j] + (s + 2) * 32);
    }
    if (s + 1 < KSTEPS) {
#pragma unroll
      for (int i = 0; i < 4; i++)
#pragma unroll
        for (int j = 0; j < 4; j++)
          acc[i][j] = __builtin_amdgcn_mfma_f32_16x16x32_bf16(aY[i], bY[j], acc[i][j], 0, 0, 0);
    }
  }

  const int rowb = lhi * 4;
#pragma unroll
  for (int j = 0; j < 4; j++) {
    const int n = n0 + wn + j * 16 + l15;
    if (n < N) {
      const float bn = (n < nsplit) ? bias[n] : bias2[n - nsplit];
#pragma unroll
      for (int i = 0; i < 4; i++) {
#pragma unroll
        for (int r = 0; r < 4; r++) {
          const long m = m0 + wm + i * 16 + rowb + r;
          float v = acc[i][j][r] + bn;
          if (RELU) v = fmaxf(v, 0.f);
          C[m * N + n] = f2b(v);
        }
      }
    }
  }
}

// ---------------- weight transpose + bf16 convert: [L][K][N] -> [L][N][K] ----------------
__global__ void wtrans_kernel(const float* __restrict__ src, unsigned short* __restrict__ dst,
                              int K, int N, size_t src_lstride, size_t dst_lstride) {
  __shared__ float t[32][33];
  const int tx = threadIdx.x, ty = threadIdx.y;
  const int n0 = blockIdx.x * 32, k0 = blockIdx.y * 32, l = blockIdx.z;
  src += (size_t)l * src_lstride;
  dst += (size_t)l * dst_lstride;
#pragma unroll
  for (int i = 0; i < 4; i++) t[ty * 4 + i][tx] = src[(size_t)(k0 + ty * 4 + i) * N + n0 + tx];
  __syncthreads();
#pragma unroll
  for (int i = 0; i < 4; i++)
    dst[(size_t)(n0 + ty * 4 + i) * K + k0 + tx] = f2b(t[tx][ty * 4 + i]);
}

// ---------------- flatten [B,C,H,W] -> [B,HW,C]; writes out f32/b16, pos b16, q b16 ----
__global__ void flatten_kernel(const float* __restrict__ src, const float* __restrict__ pos,
                               const float* __restrict__ lemb, float* __restrict__ outf,
                               unsigned short* __restrict__ outb, unsigned short* __restrict__ posb,
                               unsigned short* __restrict__ qb, int HW, int s0) {
  __shared__ float ts[32][33];
  __shared__ float tp[32][33];
  const int tx = threadIdx.x, ty = threadIdx.y;
  const int hw0 = blockIdx.x * 32, c0 = blockIdx.y * 32, b = blockIdx.z;
  const size_t ibase = ((size_t)b * 256 + c0) * HW + hw0;
#pragma unroll
  for (int i = 0; i < 4; i++) {
    ts[ty * 4 + i][tx] = src[ibase + (size_t)(ty * 4 + i) * HW + tx];
    tp[ty * 4 + i][tx] = pos[ibase + (size_t)(ty * 4 + i) * HW + tx];
  }
  __syncthreads();
#pragma unroll
  for (int i = 0; i < 4; i++) {
    const int sI = s0 + hw0 + ty * 4 + i, c = c0 + tx;
    const size_t o = ((size_t)b * S_TOT + sI) * 256 + c;
    const float sv = ts[tx][ty * 4 + i];
    const unsigned short pb = f2b(tp[tx][ty * 4 + i] + lemb[c]);
    outf[o] = sv;
    outb[o] = f2b(sv);
    posb[o] = pb;
    qb[o] = f2b(sv + b2f(pb));
  }
}

// ---------------- deformable attention sampling (oa = fused [offs(192) | aw(96)]) ----------
__global__ __launch_bounds__(256) void deform_kernel(const unsigned short* __restrict__ value,
                                                     const unsigned short* __restrict__ oa,
                                                     unsigned short* __restrict__ attn) {
  __shared__ float law[4][96];
  __shared__ uint4 didx[4][96];
  __shared__ float4 dwt[4][96];
  const int tid = threadIdx.x;
  const int wv = tid >> 6, lane = tid & 63;
  const int bs = blockIdx.x * 4 + wv;
  const int b = bs / S_TOT, s = bs - b * S_TOT;

  if (lane < 8) {  // per-head softmax over NL*NP=12
    const unsigned short* ap = oa + (size_t)bs * 288 + 192 + lane * 12;
    const uint2 p0 = *(const uint2*)ap;
    const uint2 p1 = *(const uint2*)(ap + 4);
    const uint2 p2 = *(const uint2*)(ap + 8);
    float a[12] = {blo(p0.x), bhi(p0.x), blo(p0.y), bhi(p0.y),
                   blo(p1.x), bhi(p1.x), blo(p1.y), bhi(p1.y),
                   blo(p2.x), bhi(p2.x), blo(p2.y), bhi(p2.y)};
    float mx = a[0];
#pragma unroll
    for (int i = 1; i < 12; i++) mx = fmaxf(mx, a[i]);
    float e[12], sm = 0.f;
#pragma unroll
    for (int i = 0; i < 12; i++) { e[i] = __expf(a[i] - mx); sm += e[i]; }
    const float r = 1.f / sm;
#pragma unroll
    for (int i = 0; i < 12; i++) law[wv][lane * 12 + i] = e[i] * r;
  }
  __syncthreads();

  float rx, ry;
  {
    if (s < 1024) { const int li = s; rx = ((li & 31) + 0.5f) * (1.f / 32); ry = ((li >> 5) + 0.5f) * (1.f / 32); }
    else if (s < 5120) { const int li = s - 1024; rx = ((li & 63) + 0.5f) * (1.f / 64); ry = ((li >> 6) + 0.5f) * (1.f / 64); }
    else { const int li = s - 5120; rx = ((li & 127) + 0.5f) * (1.f / 128); ry = ((li >> 7) + 0.5f) * (1.f / 128); }
  }

  for (int ti = lane; ti < 96; ti += 64) {
    const int h = ti / 12;
    const int rem = ti - h * 12;
    const int lvl = rem >> 2;
    const int wl = 32 << lvl;
    const float fwl = (float)wl;
    const int start = (lvl == 0) ? 0 : ((lvl == 1) ? 1024 : 5120);
    const unsigned op = *(const unsigned*)(oa + (size_t)bs * 288 + 2 * ti);
    const float ox = blo(op), oy = bhi(op);
    const float x = (rx + ox / fwl) * fwl - 0.5f;   // matches ref FP order
    const float y = (ry + oy / fwl) * fwl - 0.5f;
    const float xf = floorf(x), yf = floorf(y);
    const int x0 = (int)xf, y0 = (int)yf;
    const float fx = x - xf, fy = y - yf;
    const bool xv0 = (x0 >= 0) & (x0 < wl), xv1 = (x0 + 1 >= 0) & (x0 + 1 < wl);
    const bool yv0 = (y0 >= 0) & (y0 < wl), yv1 = (y0 + 1 >= 0) & (y0 + 1 < wl);
    const int x0c = min(max(x0, 0), wl - 1), x1c = min(max(x0 + 1, 0), wl - 1);
    const int y0c = min(max(y0, 0), wl - 1), y1c = min(max(y0 + 1, 0), wl - 1);
    const float w = law[wv][ti];
    float4 w4;
    w4.x = (xv0 & yv0) ? w * (1.f - fx) * (1.f - fy) : 0.f;
    w4.y = (xv1 & yv0) ? w * fx * (1.f - fy) : 0.f;
    w4.z = (xv0 & yv1) ? w * (1.f - fx) * fy : 0.f;
    w4.w = (xv1 & yv1) ? w * fx * fy : 0.f;
    const int base = ((b * S_TOT + start) << 8) + h * 32;
    uint4 iv;
    iv.x = base + (unsigned)(y0c * wl + x0c) * 256u;
    iv.y = base + (unsigned)(y0c * wl + x1c) * 256u;
    iv.z = base + (unsigned)(y1c * wl + x0c) * 256u;
    iv.w = base + (unsigned)(y1c * wl + x1c) * 256u;
    didx[wv][ti] = iv;
    dwt[wv][ti] = w4;
  }
  __syncthreads();

  const int h = lane >> 3, c = (lane & 7) * 4;
  const uint4* ip = &didx[wv][h * 12];
  const float4* wp = &dwt[wv][h * 12];
  f32x2 acc0 = (f32x2){0.f, 0.f}, acc1 = (f32x2){0.f, 0.f};
#pragma unroll 4
  for (int t = 0; t < 12; t++) {
    const uint4 iv = ip[t];
    const float4 w4 = wp[t];
    const uint2 q00 = *(const uint2*)(value + iv.x + c);
    const uint2 q01 = *(const uint2*)(value + iv.y + c);
    const uint2 q10 = *(const uint2*)(value + iv.z + c);
    const uint2 q11 = *(const uint2*)(value + iv.w + c);
    const f32x2 w0 = (f32x2){w4.x, w4.x}, w1 = (f32x2){w4.y, w4.y};
    const f32x2 w2 = (f32x2){w4.z, w4.z}, w3 = (f32x2){w4.w, w4.w};
    acc0 += w0 * unpk(q00.x) + w1 * unpk(q01.x) + w2 * unpk(q10.x) + w3 * unpk(q11.x);
    acc1 += w0 * unpk(q00.y) + w1 * unpk(q01.y) + w2 * unpk(q10.y) + w3 * unpk(q11.y);
  }
  uint2 o;
  o.x = (unsigned)f2b(acc0.x) | ((unsigned)f2b(acc0.y) << 16);
  o.y = (unsigned)f2b(acc1.x) | ((unsigned)f2b(acc1.y) << 16);
  *(uint2*)(attn + (size_t)bs * 256 + h * 32 + c) = o;
}

// ---------------- residual + layernorm (one wave per token); r is bf16 ----------------
__global__ __launch_bounds__(256) void resln_kernel(const float* __restrict__ x,
                                                    const unsigned short* __restrict__ r,
                                                    const float* __restrict__ g,
                                                    const float* __restrict__ bta,
                                                    float* __restrict__ of,
                                                    unsigned short* __restrict__ ob,
                                                    const unsigned short* __restrict__ pos,
                                                    unsigned short* __restrict__ qb) {
  const int t = blockIdx.x * 4 + (threadIdx.x >> 6);
  const int lane = threadIdx.x & 63;
  const size_t base = (size_t)t * 256;
  const float4 xv = ((const float4*)(x + base))[lane];
  const ushort4 rv = ((const ushort4*)(r + base))[lane];
  const float v0 = xv.x + b2f(rv.x), v1 = xv.y + b2f(rv.y);
  const float v2 = xv.z + b2f(rv.z), v3 = xv.w + b2f(rv.w);
  float sm = v0 + v1 + v2 + v3;
#pragma unroll
  for (int o = 32; o > 0; o >>= 1) sm += __shfl_xor(sm, o);
  const float mean = sm * (1.f / 256.f);
  const float d0 = v0 - mean, d1 = v1 - mean, d2 = v2 - mean, d3 = v3 - mean;
  float vs = d0 * d0 + d1 * d1 + d2 * d2 + d3 * d3;
#pragma unroll
  for (int o = 32; o > 0; o >>= 1) vs += __shfl_xor(vs, o);
  const float inv = rsqrtf(vs * (1.f / 256.f) + 1e-5f);
  const int c = lane * 4;
  const float o0 = d0 * inv * g[c] + bta[c];
  const float o1 = d1 * inv * g[c + 1] + bta[c + 1];
  const float o2 = d2 * inv * g[c + 2] + bta[c + 2];
  const float o3 = d3 * inv * g[c + 3] + bta[c + 3];
  ((float4*)(of + base))[lane] = make_float4(o0, o1, o2, o3);
  if (ob) {
    ushort4 u;
    u.x = f2b(o0); u.y = f2b(o1); u.z = f2b(o2); u.w = f2b(o3);
    ((ushort4*)(ob + base))[lane] = u;
  }
  if (qb) {
    const ushort4 pv = ((const ushort4*)(pos + base))[lane];
    ushort4 u;
    u.x = f2b(o0 + b2f(pv.x)); u.y = f2b(o1 + b2f(pv.y));
    u.z = f2b(o2 + b2f(pv.z)); u.w = f2b(o3 + b2f(pv.w));
    ((ushort4*)(qb + base))[lane] = u;
  }
}

// ---------------- host ----------------
extern "C" void kernel_launch(void* const* d_in, const int* in_sizes, int n_in,
                              void* d_out, int out_size, void* d_ws, size_t ws_size,
                              hipStream_t stream) {
  (void)in_sizes; (void)n_in; (void)out_size;
  const float* src0 = (const float*)d_in[0];
  const float* pos0 = (const float*)d_in[1];
  const float* src1 = (const float*)d_in[2];
  const float* pos1 = (const float*)d_in[3];
  const float* src2 = (const float*)d_in[4];
  const float* pos2 = (const float*)d_in[5];
  const float* lemb = (const float*)d_in[6];
  const float* Wv = (const float*)d_in[7];   const float* bv = (const float*)d_in[8];
  const float* Wo = (const float*)d_in[9];   const float* bo = (const float*)d_in[10];
  const float* Wa = (const float*)d_in[11];  const float* ba = (const float*)d_in[12];
  const float* Wout = (const float*)d_in[13]; const float* bout = (const float*)d_in[14];
  const float* ln1g = (const float*)d_in[15]; const float* ln1b = (const float*)d_in[16];
  const float* W1 = (const float*)d_in[17];  const float* b1 = (const float*)d_in[18];
  const float* W2 = (const float*)d_in[19];  const float* b2 = (const float*)d_in[20];
  const float* ln2g = (const float*)d_in[21]; const float* ln2b = (const float*)d_in[22];

  const size_t M = M_TOK;
  const size_t NEED = 44040192ull + 176160768ull + 44040192ull + 44040192ull + 8749056ull;
  if (ws_size < NEED) return;

  char* ws = (char*)d_ws;
  unsigned short* buf16 = (unsigned short*)ws;      ws += 44040192ull;
  char* ov = ws;                                    ws += 176160768ull;
  unsigned short* q_b16 = (unsigned short*)ov;
  unsigned short* oa_b16 = (unsigned short*)ov + M * 256;   // [M,288]: offs(192)|aw(96)
  unsigned short* attn_b16 = (unsigned short*)ov + M * 544;
  unsigned short* h_b16 = (unsigned short*)ov;  // clobbers q/oa/attn (dead by then)
  unsigned short* out_b16 = (unsigned short*)ws;    ws += 44040192ull;
  unsigned short* pos_b16 = (unsigned short*)ws;    ws += 44040192ull;
  unsigned short* wt = (unsigned short*)ws;

  unsigned short* wtv = wt;                 // [6][256][256]
  unsigned short* wtoa = wt + 393216;       // [6][288][256] (Wo rows 0..191, Wa rows 192..287)
  unsigned short* wtw = wt + 835584;        // [6][256][256]
  unsigned short* wt1 = wt + 1228800;       // [6][1024][256]
  unsigned short* wt2 = wt + 2801664;       // [6][256][1024]

  float* out_f32 = (float*)d_out;  // residual stream lives in d_out

  const dim3 b32(32, 8);
  wtrans_kernel<<<dim3(8, 8, 6), b32, 0, stream>>>(Wv, wtv, 256, 256, 65536, 65536);
  wtrans_kernel<<<dim3(6, 8, 6), b32, 0, stream>>>(Wo, wtoa, 256, 192, 49152, 73728);
  wtrans_kernel<<<dim3(3, 8, 6), b32, 0, stream>>>(Wa, wtoa + 192 * 256, 256, 96, 24576, 73728);
  wtrans_kernel<<<dim3(8, 8, 6), b32, 0, stream>>>(Wout, wtw, 256, 256, 65536, 65536);
  wtrans_kernel<<<dim3(32, 8, 6), b32, 0, stream>>>(W1, wt1, 256, 1024, 262144, 262144);
  wtrans_kernel<<<dim3(8, 32, 6), b32, 0, stream>>>(W2, wt2, 1024, 256, 262144, 262144);

  flatten_kernel<<<dim3(32, 8, 4), b32, 0, stream>>>(src0, pos0, lemb, out_f32, out_b16, pos_b16, q_b16, 1024, 0);
  flatten_kernel<<<dim3(128, 8, 4), b32, 0, stream>>>(src1, pos1, lemb + 256, out_f32, out_b16, pos_b16, q_b16, 4096, 1024);
  flatten_kernel<<<dim3(512, 8, 4), b32, 0, stream>>>(src2, pos2, lemb + 512, out_f32, out_b16, pos_b16, q_b16, 16384, 5120);

  for (int l = 0; l < 6; l++) {
    gemm_direct<0, 8><<<dim3(672, 2), 256, 0, stream>>>(out_b16, wtv + l * 65536, bv + l * 256, bv + l * 256, 256, buf16, 256);
    gemm_direct<0, 8><<<dim3(672, 3), 256, 0, stream>>>(q_b16, wtoa + l * 73728, bo + l * 192, ba + l * 96, 192, oa_b16, 288);
    deform_kernel<<<21504, 256, 0, stream>>>(buf16, oa_b16, attn_b16);
    gemm_direct<0, 8><<<dim3(672, 2), 256, 0, stream>>>(attn_b16, wtw + l * 65536, bout + l * 256, bout + l * 256, 256, buf16, 256);
    resln_kernel<<<21504, 256, 0, stream>>>(out_f32, buf16, ln1g + l * 256, ln1b + l * 256, out_f32, out_b16, nullptr, nullptr);
    gemm_direct<1, 8><<<dim3(672, 8), 256, 0, stream>>>(out_b16, wt1 + l * 262144, b1 + l * 1024, b1 + l * 1024, 1024, h_b16, 1024);
    gemm_direct<0, 32><<<dim3(672, 2), 256, 0, stream>>>(h_b16, wt2 + l * 262144, b2 + l * 256, b2 + l * 256, 256, buf16, 256);
    resln_kernel<<<21504, 256, 0, stream>>>(out_f32, buf16, ln2g + l * 256, ln2b + l * 256, out_f32,
                                            (l == 5) ? nullptr : out_b16,
                                            (l == 5) ? nullptr : pos_b16,
                                            (l == 5) ? nullptr : q_b16);
  }
}

// Round 8
// 3026.109 us; speedup vs baseline: 1.9503x; 1.5599x over previous
//
#include <hip/hip_runtime.h>
#include <stdint.h>

// ---------------- static problem config ----------------
#define S_TOT 21504
#define M_TOK 86016
// levels: (32,32) start 0, (64,64) start 1024, (128,128) start 5120

typedef __attribute__((ext_vector_type(8))) short bf16x8;
typedef __attribute__((ext_vector_type(4))) float f32x4;
typedef __attribute__((ext_vector_type(2))) float f32x2;

__device__ __forceinline__ unsigned short f2b(float f) {
  union { float f; unsigned u; } v; v.f = f;
  unsigned r = v.u + 0x7FFFu + ((v.u >> 16) & 1u);
  return (unsigned short)(r >> 16);
}
__device__ __forceinline__ float b2f(unsigned short h) {
  union { unsigned u; float f; } v; v.u = ((unsigned)h) << 16;
  return v.f;
}
__device__ __forceinline__ float blo(unsigned u) {
  union { unsigned u; float f; } v; v.u = u << 16; return v.f;
}
__device__ __forceinline__ float bhi(unsigned u) {
  union { unsigned u; float f; } v; v.u = u & 0xffff0000u; return v.f;
}
__device__ __forceinline__ f32x2 unpk(unsigned u) {
  union { unsigned u; float f; } lo, hi;
  lo.u = u << 16; hi.u = u & 0xffff0000u;
  return (f32x2){lo.f, hi.f};
}

// ---------------- bf16 MFMA GEMM: C[M,N] = A[M,K] * Bt[N,K]^T + bias ----------------
// ROUND-3 STRUCTURE RESTORED VERBATIM (best measured: 445 TF avg, total 3348 us).
// BM=BN=128, BK=32, 256 threads (4 waves, 64x64 quadrant each).
// Register-staged global->LDS with next-tile reg prefetch under the MFMAs.
template <int RELU>
__global__ __launch_bounds__(256) void gemm_kernel(
    const unsigned short* __restrict__ A, const unsigned short* __restrict__ Bt,
    const float* __restrict__ bias, const float* __restrict__ bias2, int nsplit,
    unsigned short* __restrict__ C, int N, int K) {
  __shared__ unsigned short Alds[128 * 32];
  __shared__ unsigned short Blds[128 * 32];
  const int tid = threadIdx.x;
  const int wave = tid >> 6, lane = tid & 63;
  const long m0 = (long)blockIdx.x * 128;
  const int n0 = blockIdx.y * 128;
  const int wm = (wave >> 1) * 64, wn = (wave & 1) * 64;

  f32x4 acc[4][4];
#pragma unroll
  for (int i = 0; i < 4; i++)
#pragma unroll
    for (int j = 0; j < 4; j++) acc[i][j] = (f32x4){0.f, 0.f, 0.f, 0.f};

  // chunk tid covers tile row tid>>2, k-range (tid&3)*8..+7 (16B); 2nd chunk = +64 rows
  const int ar = tid >> 2, ak = (tid & 3) * 8;
  int brA = n0 + ar;      if (brA >= N) brA = N - 1;  // clamp OOB weight rows
  int brB = n0 + ar + 64; if (brB >= N) brB = N - 1;
  const unsigned short* a0p = A + (m0 + ar) * (long)K + ak;
  const unsigned short* a1p = A + (m0 + ar + 64) * (long)K + ak;
  const unsigned short* b0p = Bt + (long)brA * K + ak;
  const unsigned short* b1p = Bt + (long)brB * K + ak;

  uint4 a0 = *(const uint4*)a0p;
  uint4 a1 = *(const uint4*)a1p;
  uint4 b0 = *(const uint4*)b0p;
  uint4 b1 = *(const uint4*)b1p;

  for (int k0 = 0; k0 < K; k0 += 32) {
    if (k0) __syncthreads();  // previous iteration's frag reads must finish
    ((uint4*)Alds)[tid] = a0;
    ((uint4*)Alds)[tid + 256] = a1;
    ((uint4*)Blds)[tid] = b0;
    ((uint4*)Blds)[tid + 256] = b1;
    if (k0 + 32 < K) {  // prefetch next K-tile into regs; hides under MFMA below
      a0 = *(const uint4*)(a0p + k0 + 32);
      a1 = *(const uint4*)(a1p + k0 + 32);
      b0 = *(const uint4*)(b0p + k0 + 32);
      b1 = *(const uint4*)(b1p + k0 + 32);
    }
    __syncthreads();

    const int kk = (lane >> 4) * 8;
    bf16x8 af[4], bq[4];
#pragma unroll
    for (int i = 0; i < 4; i++)
      af[i] = *(const bf16x8*)&Alds[(wm + i * 16 + (lane & 15)) * 32 + kk];
#pragma unroll
    for (int j = 0; j < 4; j++)
      bq[j] = *(const bf16x8*)&Blds[(wn + j * 16 + (lane & 15)) * 32 + kk];
#pragma unroll
    for (int i = 0; i < 4; i++)
#pragma unroll
      for (int j = 0; j < 4; j++)
        acc[i][j] = __builtin_amdgcn_mfma_f32_16x16x32_bf16(af[i], bq[j], acc[i][j], 0, 0, 0);
  }

  const int colb = lane & 15, rowb = (lane >> 4) * 4;
#pragma unroll
  for (int j = 0; j < 4; j++) {
    const int n = n0 + wn + j * 16 + colb;
    if (n < N) {
      const float bn = (n < nsplit) ? bias[n] : bias2[n - nsplit];
#pragma unroll
      for (int i = 0; i < 4; i++) {
#pragma unroll
        for (int r = 0; r < 4; r++) {
          const long m = m0 + wm + i * 16 + rowb + r;
          float v = acc[i][j][r] + bn;
          if (RELU) v = fmaxf(v, 0.f);
          C[m * N + n] = f2b(v);
        }
      }
    }
  }
}

// ---------------- weight transpose + bf16 convert: [L][K][N] -> [L][N][K] ----------------
__global__ void wtrans_kernel(const float* __restrict__ src, unsigned short* __restrict__ dst,
                              int K, int N, size_t src_lstride, size_t dst_lstride) {
  __shared__ float t[32][33];
  const int tx = threadIdx.x, ty = threadIdx.y;
  const int n0 = blockIdx.x * 32, k0 = blockIdx.y * 32, l = blockIdx.z;
  src += (size_t)l * src_lstride;
  dst += (size_t)l * dst_lstride;
#pragma unroll
  for (int i = 0; i < 4; i++) t[ty * 4 + i][tx] = src[(size_t)(k0 + ty * 4 + i) * N + n0 + tx];
  __syncthreads();
#pragma unroll
  for (int i = 0; i < 4; i++)
    dst[(size_t)(n0 + ty * 4 + i) * K + k0 + tx] = f2b(t[tx][ty * 4 + i]);
}

// ---------------- flatten [B,C,H,W] -> [B,HW,C]; writes residual b16, pos b16, q b16 ----
__global__ void flatten_kernel(const float* __restrict__ src, const float* __restrict__ pos,
                               const float* __restrict__ lemb,
                               unsigned short* __restrict__ outb, unsigned short* __restrict__ posb,
                               unsigned short* __restrict__ qb, int HW, int s0) {
  __shared__ float ts[32][33];
  __shared__ float tp[32][33];
  const int tx = threadIdx.x, ty = threadIdx.y;
  const int hw0 = blockIdx.x * 32, c0 = blockIdx.y * 32, b = blockIdx.z;
  const size_t ibase = ((size_t)b * 256 + c0) * HW + hw0;
#pragma unroll
  for (int i = 0; i < 4; i++) {
    ts[ty * 4 + i][tx] = src[ibase + (size_t)(ty * 4 + i) * HW + tx];
    tp[ty * 4 + i][tx] = pos[ibase + (size_t)(ty * 4 + i) * HW + tx];
  }
  __syncthreads();
#pragma unroll
  for (int i = 0; i < 4; i++) {
    const int sI = s0 + hw0 + ty * 4 + i, c = c0 + tx;
    const size_t o = ((size_t)b * S_TOT + sI) * 256 + c;
    const float sv = ts[tx][ty * 4 + i];
    const unsigned short pb = f2b(tp[tx][ty * 4 + i] + lemb[c]);
    outb[o] = f2b(sv);
    posb[o] = pb;
    qb[o] = f2b(sv + b2f(pb));
  }
}

// ---------------- deformable attention sampling (oa = fused [offs(192) | aw(96)]) ----------
__global__ __launch_bounds__(256) void deform_kernel(const unsigned short* __restrict__ value,
                                                     const unsigned short* __restrict__ oa,
                                                     unsigned short* __restrict__ attn) {
  __shared__ float law[4][96];
  __shared__ uint4 didx[4][96];
  __shared__ float4 dwt[4][96];
  const int tid = threadIdx.x;
  const int wv = tid >> 6, lane = tid & 63;
  const int bs = blockIdx.x * 4 + wv;
  const int b = bs / S_TOT, s = bs - b * S_TOT;

  if (lane < 8) {  // per-head softmax over NL*NP=12
    const unsigned short* ap = oa + (size_t)bs * 288 + 192 + lane * 12;
    const uint2 p0 = *(const uint2*)ap;
    const uint2 p1 = *(const uint2*)(ap + 4);
    const uint2 p2 = *(const uint2*)(ap + 8);
    float a[12] = {blo(p0.x), bhi(p0.x), blo(p0.y), bhi(p0.y),
                   blo(p1.x), bhi(p1.x), blo(p1.y), bhi(p1.y),
                   blo(p2.x), bhi(p2.x), blo(p2.y), bhi(p2.y)};
    float mx = a[0];
#pragma unroll
    for (int i = 1; i < 12; i++) mx = fmaxf(mx, a[i]);
    float e[12], sm = 0.f;
#pragma unroll
    for (int i = 0; i < 12; i++) { e[i] = __expf(a[i] - mx); sm += e[i]; }
    const float r = 1.f / sm;
#pragma unroll
    for (int i = 0; i < 12; i++) law[wv][lane * 12 + i] = e[i] * r;
  }
  __syncthreads();

  float rx, ry;
  {
    if (s < 1024) { const int li = s; rx = ((li & 31) + 0.5f) * (1.f / 32); ry = ((li >> 5) + 0.5f) * (1.f / 32); }
    else if (s < 5120) { const int li = s - 1024; rx = ((li & 63) + 0.5f) * (1.f / 64); ry = ((li >> 6) + 0.5f) * (1.f / 64); }
    else { const int li = s - 5120; rx = ((li & 127) + 0.5f) * (1.f / 128); ry = ((li >> 7) + 0.5f) * (1.f / 128); }
  }

  for (int ti = lane; ti < 96; ti += 64) {
    const int h = ti / 12;
    const int rem = ti - h * 12;
    const int lvl = rem >> 2;
    const int wl = 32 << lvl;
    const float fwl = (float)wl;
    const int start = (lvl == 0) ? 0 : ((lvl == 1) ? 1024 : 5120);
    const unsigned op = *(const unsigned*)(oa + (size_t)bs * 288 + 2 * ti);
    const float ox = blo(op), oy = bhi(op);
    const float x = (rx + ox / fwl) * fwl - 0.5f;   // matches ref FP order
    const float y = (ry + oy / fwl) * fwl - 0.5f;
    const float xf = floorf(x), yf = floorf(y);
    const int x0 = (int)xf, y0 = (int)yf;
    const float fx = x - xf, fy = y - yf;
    const bool xv0 = (x0 >= 0) & (x0 < wl), xv1 = (x0 + 1 >= 0) & (x0 + 1 < wl);
    const bool yv0 = (y0 >= 0) & (y0 < wl), yv1 = (y0 + 1 >= 0) & (y0 + 1 < wl);
    const int x0c = min(max(x0, 0), wl - 1), x1c = min(max(x0 + 1, 0), wl - 1);
    const int y0c = min(max(y0, 0), wl - 1), y1c = min(max(y0 + 1, 0), wl - 1);
    const float w = law[wv][ti];
    float4 w4;
    w4.x = (xv0 & yv0) ? w * (1.f - fx) * (1.f - fy) : 0.f;
    w4.y = (xv1 & yv0) ? w * fx * (1.f - fy) : 0.f;
    w4.z = (xv0 & yv1) ? w * (1.f - fx) * fy : 0.f;
    w4.w = (xv1 & yv1) ? w * fx * fy : 0.f;
    const int base = ((b * S_TOT + start) << 8) + h * 32;
    uint4 iv;
    iv.x = base + (unsigned)(y0c * wl + x0c) * 256u;
    iv.y = base + (unsigned)(y0c * wl + x1c) * 256u;
    iv.z = base + (unsigned)(y1c * wl + x0c) * 256u;
    iv.w = base + (unsigned)(y1c * wl + x1c) * 256u;
    didx[wv][ti] = iv;
    dwt[wv][ti] = w4;
  }
  __syncthreads();

  const int h = lane >> 3, c = (lane & 7) * 4;
  const uint4* ip = &didx[wv][h * 12];
  const float4* wp = &dwt[wv][h * 12];
  f32x2 acc0 = (f32x2){0.f, 0.f}, acc1 = (f32x2){0.f, 0.f};
#pragma unroll 4
  for (int t = 0; t < 12; t++) {
    const uint4 iv = ip[t];
    const float4 w4 = wp[t];
    const uint2 q00 = *(const uint2*)(value + iv.x + c);
    const uint2 q01 = *(const uint2*)(value + iv.y + c);
    const uint2 q10 = *(const uint2*)(value + iv.z + c);
    const uint2 q11 = *(const uint2*)(value + iv.w + c);
    const f32x2 w0 = (f32x2){w4.x, w4.x}, w1 = (f32x2){w4.y, w4.y};
    const f32x2 w2 = (f32x2){w4.z, w4.z}, w3 = (f32x2){w4.w, w4.w};
    acc0 += w0 * unpk(q00.x) + w1 * unpk(q01.x) + w2 * unpk(q10.x) + w3 * unpk(q11.x);
    acc1 += w0 * unpk(q00.y) + w1 * unpk(q01.y) + w2 * unpk(q10.y) + w3 * unpk(q11.y);
  }
  uint2 o;
  o.x = (unsigned)f2b(acc0.x) | ((unsigned)f2b(acc0.y) << 16);
  o.y = (unsigned)f2b(acc1.x) | ((unsigned)f2b(acc1.y) << 16);
  *(uint2*)(attn + (size_t)bs * 256 + h * 32 + c) = o;
}

// ---------------- residual + layernorm; bf16 residual stream (in-place) ----------------
// x, r bf16; LN math f32. Writes ob (bf16, layers 0..4) or fout (f32, final layer);
// optionally q = bf16(LN_out + pos).
__global__ __launch_bounds__(256) void resln_kernel(const unsigned short* __restrict__ x,
                                                    const unsigned short* __restrict__ r,
                                                    const float* __restrict__ g,
                                                    const float* __restrict__ bta,
                                                    unsigned short* __restrict__ ob,
                                                    const unsigned short* __restrict__ pos,
                                                    unsigned short* __restrict__ qb,
                                                    float* __restrict__ fout) {
  const int t = blockIdx.x * 4 + (threadIdx.x >> 6);
  const int lane = threadIdx.x & 63;
  const size_t base = (size_t)t * 256;
  const ushort4 xv = ((const ushort4*)(x + base))[lane];
  const ushort4 rv = ((const ushort4*)(r + base))[lane];
  const float v0 = b2f(xv.x) + b2f(rv.x), v1 = b2f(xv.y) + b2f(rv.y);
  const float v2 = b2f(xv.z) + b2f(rv.z), v3 = b2f(xv.w) + b2f(rv.w);
  float sm = v0 + v1 + v2 + v3;
#pragma unroll
  for (int o = 32; o > 0; o >>= 1) sm += __shfl_xor(sm, o);
  const float mean = sm * (1.f / 256.f);
  const float d0 = v0 - mean, d1 = v1 - mean, d2 = v2 - mean, d3 = v3 - mean;
  float vs = d0 * d0 + d1 * d1 + d2 * d2 + d3 * d3;
#pragma unroll
  for (int o = 32; o > 0; o >>= 1) vs += __shfl_xor(vs, o);
  const float inv = rsqrtf(vs * (1.f / 256.f) + 1e-5f);
  const int c = lane * 4;
  const float o0 = d0 * inv * g[c] + bta[c];
  const float o1 = d1 * inv * g[c + 1] + bta[c + 1];
  const float o2 = d2 * inv * g[c + 2] + bta[c + 2];
  const float o3 = d3 * inv * g[c + 3] + bta[c + 3];
  if (fout) {
    ((float4*)(fout + base))[lane] = make_float4(o0, o1, o2, o3);
  } else {
    ushort4 u;
    u.x = f2b(o0); u.y = f2b(o1); u.z = f2b(o2); u.w = f2b(o3);
    ((ushort4*)(ob + base))[lane] = u;
  }
  if (qb) {
    const ushort4 pv = ((const ushort4*)(pos + base))[lane];
    ushort4 u;
    u.x = f2b(o0 + b2f(pv.x)); u.y = f2b(o1 + b2f(pv.y));
    u.z = f2b(o2 + b2f(pv.z)); u.w = f2b(o3 + b2f(pv.w));
    ((ushort4*)(qb + base))[lane] = u;
  }
}

// ---------------- host ----------------
extern "C" void kernel_launch(void* const* d_in, const int* in_sizes, int n_in,
                              void* d_out, int out_size, void* d_ws, size_t ws_size,
                              hipStream_t stream) {
  (void)in_sizes; (void)n_in; (void)out_size;
  const float* src0 = (const float*)d_in[0];
  const float* pos0 = (const float*)d_in[1];
  const float* src1 = (const float*)d_in[2];
  const float* pos1 = (const float*)d_in[3];
  const float* src2 = (const float*)d_in[4];
  const float* pos2 = (const float*)d_in[5];
  const float* lemb = (const float*)d_in[6];
  const float* Wv = (const float*)d_in[7];   const float* bv = (const float*)d_in[8];
  const float* Wo = (const float*)d_in[9];   const float* bo = (const float*)d_in[10];
  const float* Wa = (const float*)d_in[11];  const float* ba = (const float*)d_in[12];
  const float* Wout = (const float*)d_in[13]; const float* bout = (const float*)d_in[14];
  const float* ln1g = (const float*)d_in[15]; const float* ln1b = (const float*)d_in[16];
  const float* W1 = (const float*)d_in[17];  const float* b1 = (const float*)d_in[18];
  const float* W2 = (const float*)d_in[19];  const float* b2 = (const float*)d_in[20];
  const float* ln2g = (const float*)d_in[21]; const float* ln2b = (const float*)d_in[22];

  const size_t M = M_TOK;
  const size_t NEED = 44040192ull + 176160768ull + 44040192ull + 44040192ull + 8749056ull;
  if (ws_size < NEED) return;

  char* ws = (char*)d_ws;
  unsigned short* buf16 = (unsigned short*)ws;      ws += 44040192ull;
  char* ov = ws;                                    ws += 176160768ull;
  unsigned short* q_b16 = (unsigned short*)ov;
  unsigned short* oa_b16 = (unsigned short*)ov + M * 256;   // [M,288]: offs(192)|aw(96)
  unsigned short* attn_b16 = (unsigned short*)ov + M * 544;
  unsigned short* h_b16 = (unsigned short*)ov;  // clobbers q/oa/attn (dead by then)
  unsigned short* out_b16 = (unsigned short*)ws;    ws += 44040192ull;  // bf16 residual stream
  unsigned short* pos_b16 = (unsigned short*)ws;    ws += 44040192ull;
  unsigned short* wt = (unsigned short*)ws;

  unsigned short* wtv = wt;                 // [6][256][256]
  unsigned short* wtoa = wt + 393216;       // [6][288][256] (Wo rows 0..191, Wa rows 192..287)
  unsigned short* wtw = wt + 835584;        // [6][256][256]
  unsigned short* wt1 = wt + 1228800;       // [6][1024][256]
  unsigned short* wt2 = wt + 2801664;       // [6][256][1024]

  const dim3 b32(32, 8);
  wtrans_kernel<<<dim3(8, 8, 6), b32, 0, stream>>>(Wv, wtv, 256, 256, 65536, 65536);
  wtrans_kernel<<<dim3(6, 8, 6), b32, 0, stream>>>(Wo, wtoa, 256, 192, 49152, 73728);
  wtrans_kernel<<<dim3(3, 8, 6), b32, 0, stream>>>(Wa, wtoa + 192 * 256, 256, 96, 24576, 73728);
  wtrans_kernel<<<dim3(8, 8, 6), b32, 0, stream>>>(Wout, wtw, 256, 256, 65536, 65536);
  wtrans_kernel<<<dim3(32, 8, 6), b32, 0, stream>>>(W1, wt1, 256, 1024, 262144, 262144);
  wtrans_kernel<<<dim3(8, 32, 6), b32, 0, stream>>>(W2, wt2, 1024, 256, 262144, 262144);

  flatten_kernel<<<dim3(32, 8, 4), b32, 0, stream>>>(src0, pos0, lemb, out_b16, pos_b16, q_b16, 1024, 0);
  flatten_kernel<<<dim3(128, 8, 4), b32, 0, stream>>>(src1, pos1, lemb + 256, out_b16, pos_b16, q_b16, 4096, 1024);
  flatten_kernel<<<dim3(512, 8, 4), b32, 0, stream>>>(src2, pos2, lemb + 512, out_b16, pos_b16, q_b16, 16384, 5120);

  for (int l = 0; l < 6; l++) {
    gemm_kernel<0><<<dim3(672, 2), 256, 0, stream>>>(out_b16, wtv + l * 65536, bv + l * 256, bv + l * 256, 256, buf16, 256, 256);
    gemm_kernel<0><<<dim3(672, 3), 256, 0, stream>>>(q_b16, wtoa + l * 73728, bo + l * 192, ba + l * 96, 192, oa_b16, 288, 256);
    deform_kernel<<<21504, 256, 0, stream>>>(buf16, oa_b16, attn_b16);
    gemm_kernel<0><<<dim3(672, 2), 256, 0, stream>>>(attn_b16, wtw + l * 65536, bout + l * 256, bout + l * 256, 256, buf16, 256, 256);
    resln_kernel<<<21504, 256, 0, stream>>>(out_b16, buf16, ln1g + l * 256, ln1b + l * 256, out_b16, nullptr, nullptr, nullptr);
    gemm_kernel<1><<<dim3(672, 8), 256, 0, stream>>>(out_b16, wt1 + l * 262144, b1 + l * 1024, b1 + l * 1024, 1024, h_b16, 1024, 256);
    gemm_kernel<0><<<dim3(672, 2), 256, 0, stream>>>(h_b16, wt2 + l * 262144, b2 + l * 256, b2 + l * 256, 256, buf16, 256, 1024);
    if (l < 5) {
      resln_kernel<<<21504, 256, 0, stream>>>(out_b16, buf16, ln2g + l * 256, ln2b + l * 256, out_b16, pos_b16, q_b16, nullptr);
    } else {
      resln_kernel<<<21504, 256, 0, stream>>>(out_b16, buf16, ln2g + l * 256, ln2b + l * 256, nullptr, nullptr, nullptr, (float*)d_out);
    }
  }
}